// Round 1
// 464.419 us; speedup vs baseline: 1.1585x; 1.1585x over previous
//
#include <hip/hip_runtime.h>
#include <hip/hip_bf16.h>

// Problem constants (fixed by the reference)
#define Bn   4
#define Sn   1024
#define Dn   1024
#define Hn   16
#define dHn  64
#define HB   (Hn * Bn)     // 64
#define MROWS (Bn * Sn)    // 4096
#define QNE  ((size_t)Bn * Sn * Dn)   // 4M elements per activation tensor

typedef __attribute__((ext_vector_type(8))) short bf16x8;
typedef __attribute__((ext_vector_type(4))) float f32x4;

__device__ __forceinline__ ushort f2bf(float x) {
  union { float f; unsigned u; } v; v.f = x;
  unsigned r = v.u + 0x7FFF + ((v.u >> 16) & 1);   // round-to-nearest-even
  return (ushort)(r >> 16);
}
__device__ __forceinline__ float bf2f(ushort u) {
  union { unsigned u; float f; } v; v.u = ((unsigned)u) << 16; return v.f;
}

// async global->LDS, 16B per lane; lds dest = wave-uniform base + lane*16
__device__ __forceinline__ void load_lds16(const void* g, void* l) {
  __builtin_amdgcn_global_load_lds(
      (const __attribute__((address_space(1))) unsigned int*)g,
      (__attribute__((address_space(3))) unsigned int*)l, 16, 0, 0);
}

// ---------------------------------------------------------------------------
// fp32 -> bf16 flat cast for q,k,v in ONE launch.  grid (QNE/1024, 3).
// Outputs are contiguous in ws: qbf | kbf | vbf.
// ---------------------------------------------------------------------------
__global__ __launch_bounds__(256) void cast3_kernel(
    const float* __restrict__ q, const float* __restrict__ k,
    const float* __restrict__ v, ushort* __restrict__ outb) {
  const float* in = blockIdx.y == 0 ? q : (blockIdx.y == 1 ? k : v);
  ushort* out = outb + (size_t)blockIdx.y * QNE;
  int idx = blockIdx.x * 256 + threadIdx.x;   // float4 index
  float4 x = *(const float4*)&in[(size_t)idx * 4];
  ushort4 o;
  o.x = f2bf(x.x); o.y = f2bf(x.y); o.z = f2bf(x.z); o.w = f2bf(x.w);
  *(ushort4*)&out[(size_t)idx * 4] = o;
}

// ---------------------------------------------------------------------------
// W [K,N] fp32 -> WT [N,K] bf16 for all 4 weights in ONE launch.
// Tile 64x64.  grid (Dn/64, Dn/64, 4).  Outputs contiguous: WqT|WkT|WvT|WoT.
// ---------------------------------------------------------------------------
__global__ __launch_bounds__(256) void transpose4_kernel(
    const float* __restrict__ Wq, const float* __restrict__ Wk,
    const float* __restrict__ Wv, const float* __restrict__ Wo,
    ushort* __restrict__ WTb) {
  const int z = blockIdx.z;
  const float* W = z == 0 ? Wq : (z == 1 ? Wk : (z == 2 ? Wv : Wo));
  ushort* WT = WTb + (size_t)z * Dn * Dn;
  __shared__ ushort T[64 * 72];   // [n][k], stride 72
  const int k0 = blockIdx.y * 64, n0 = blockIdx.x * 64;
  const int t = threadIdx.x;
  const int r = t >> 4, c4 = (t & 15) * 4;
#pragma unroll
  for (int i = 0; i < 4; ++i) {
    int row = r + i * 16;   // k within tile
    float4 v = *(const float4*)&W[(size_t)(k0 + row) * Dn + n0 + c4];
    T[(c4 + 0) * 72 + row] = f2bf(v.x);
    T[(c4 + 1) * 72 + row] = f2bf(v.y);
    T[(c4 + 2) * 72 + row] = f2bf(v.z);
    T[(c4 + 3) * 72 + row] = f2bf(v.w);
  }
  __syncthreads();
#pragma unroll
  for (int i = 0; i < 2; ++i) {
    int c = t + i * 256;
    int n = c >> 3, kg = (c & 7) * 8;
    *(ulonglong2*)&WT[(size_t)(n0 + n) * Dn + k0 + kg] =
        *(const ulonglong2*)&T[n * 72 + kg];
  }
}

// ---------------------------------------------------------------------------
// Batched QKV projection GEMM: grid (Dn/128, MROWS/128, 3) = 768 blocks
// -> ~3 blocks/CU so wave-level overlap hides the staging barrier drain
// (vs 256 blocks = 1/CU when launched separately).
// z=0: Qp = qbf@WqT^T (bf16 row-major), z=1: Kp, z=2: Vt (batch-transposed).
// A tensors, B tensors, C tensors each contiguous in ws.
// ---------------------------------------------------------------------------
__global__ __launch_bounds__(256, 3) void qkv_gemm(
    const ushort* __restrict__ Ab, const ushort* __restrict__ Bb,
    ushort* __restrict__ Cb) {
  const int z = blockIdx.z;
  const ushort* A  = Ab + (size_t)z * QNE;
  const ushort* Bt = Bb + (size_t)z * Dn * Dn;
  ushort* C        = Cb + (size_t)z * QNE;
  const int M = MROWS, N = Dn, K = Dn;

  __shared__ ushort lds[17408];   // staging 16KB; MODE1 Cs 34KB (reused)
  ushort* As = lds;          // 128 x 32 (unpadded, k-contig)
  ushort* Bs = lds + 4096;   // 128 x 32
  const int t = threadIdx.x;
  const int w = t >> 6, lane = t & 63;
  const int wr = (w >> 1) * 64, wc = (w & 1) * 64;
  const int l16 = lane & 15, quad = lane >> 4;
  const int m0 = blockIdx.y * 128, n0 = blockIdx.x * 128;
  const int srow = (lane >> 2);
  const int scol = (lane & 3) * 8;
  f32x4 acc[4][4] = {};
  for (int k0 = 0; k0 < K; k0 += 32) {
#pragma unroll
    for (int c = 0; c < 2; ++c) {
      int row = w * 32 + c * 16 + srow;
      load_lds16(&A[(size_t)(m0 + row) * K + k0 + scol],
                 &As[(size_t)w * 1024 + c * 512]);
      load_lds16(&Bt[(size_t)(n0 + row) * K + k0 + scol],
                 &Bs[(size_t)w * 1024 + c * 512]);
    }
    __syncthreads();
    bf16x8 af[4], bfr[4];
#pragma unroll
    for (int mi = 0; mi < 4; ++mi)
      af[mi] = *(const bf16x8*)&As[(wr + mi * 16 + l16) * 32 + quad * 8];
#pragma unroll
    for (int ni = 0; ni < 4; ++ni)
      bfr[ni] = *(const bf16x8*)&Bs[(wc + ni * 16 + l16) * 32 + quad * 8];
#pragma unroll
    for (int mi = 0; mi < 4; ++mi)
#pragma unroll
      for (int ni = 0; ni < 4; ++ni)
        acc[mi][ni] = __builtin_amdgcn_mfma_f32_16x16x32_bf16(
            af[mi], bfr[ni], acc[mi][ni], 0, 0, 0);
    __syncthreads();
  }
  if (z == 2) {   // Vt: C[(b*Dn + n)*Sn + s], b=m/Sn, s=m%Sn
#pragma unroll
    for (int mi = 0; mi < 4; ++mi) {
      int mb = m0 + wr + mi * 16 + quad * 4;
      int b = mb >> 10, s = mb & 1023;
#pragma unroll
      for (int ni = 0; ni < 4; ++ni) {
        int n = n0 + wc + ni * 16 + l16;
        ushort4 o;
        o.x = f2bf(acc[mi][ni][0]);
        o.y = f2bf(acc[mi][ni][1]);
        o.z = f2bf(acc[mi][ni][2]);
        o.w = f2bf(acc[mi][ni][3]);
        *(ushort4*)&C[((size_t)b * N + n) * Sn + s] = o;
      }
    }
  } else {        // Qp/Kp: bf16 row-major via LDS for coalesced stores
    ushort* Cs = lds;   // 128 x 136
#pragma unroll
    for (int mi = 0; mi < 4; ++mi)
#pragma unroll
      for (int ni = 0; ni < 4; ++ni) {
        int col = wc + ni * 16 + l16;
#pragma unroll
        for (int r = 0; r < 4; ++r)
          Cs[(wr + mi * 16 + quad * 4 + r) * 136 + col] = f2bf(acc[mi][ni][r]);
      }
    __syncthreads();
#pragma unroll
    for (int i = 0; i < 8; ++i) {
      int c = t + i * 256;
      int row = c >> 4, cg = (c & 15) * 8;
      *(ulonglong2*)&C[(size_t)(m0 + row) * N + n0 + cg] =
          *(const ulonglong2*)&Cs[row * 136 + cg];
    }
  }
}

// ---------------------------------------------------------------------------
// Output projection GEMM (BT form): C[M,N] = A[M,K] @ Bt[N,K]^T + resid,
// fp32 out.  Tile 128x128, BK=32, 4 waves.
// ---------------------------------------------------------------------------
__global__ __launch_bounds__(256) void gemm_out(
    const ushort* __restrict__ A, const ushort* __restrict__ Bt,
    const float* __restrict__ resid, float* __restrict__ C,
    int M, int N, int K) {
  __shared__ ushort lds[8192];
  ushort* As = lds;
  ushort* Bs = lds + 4096;
  const int t = threadIdx.x;
  const int w = t >> 6, lane = t & 63;
  const int wr = (w >> 1) * 64, wc = (w & 1) * 64;
  const int l16 = lane & 15, quad = lane >> 4;
  const int m0 = blockIdx.y * 128, n0 = blockIdx.x * 128;
  const int srow = (lane >> 2);
  const int scol = (lane & 3) * 8;
  f32x4 acc[4][4] = {};
  for (int k0 = 0; k0 < K; k0 += 32) {
#pragma unroll
    for (int c = 0; c < 2; ++c) {
      int row = w * 32 + c * 16 + srow;
      load_lds16(&A[(size_t)(m0 + row) * K + k0 + scol],
                 &As[(size_t)w * 1024 + c * 512]);
      load_lds16(&Bt[(size_t)(n0 + row) * K + k0 + scol],
                 &Bs[(size_t)w * 1024 + c * 512]);
    }
    __syncthreads();
    bf16x8 af[4], bfr[4];
#pragma unroll
    for (int mi = 0; mi < 4; ++mi)
      af[mi] = *(const bf16x8*)&As[(wr + mi * 16 + l16) * 32 + quad * 8];
#pragma unroll
    for (int ni = 0; ni < 4; ++ni)
      bfr[ni] = *(const bf16x8*)&Bs[(wc + ni * 16 + l16) * 32 + quad * 8];
#pragma unroll
    for (int mi = 0; mi < 4; ++mi)
#pragma unroll
      for (int ni = 0; ni < 4; ++ni)
        acc[mi][ni] = __builtin_amdgcn_mfma_f32_16x16x32_bf16(
            af[mi], bfr[ni], acc[mi][ni], 0, 0, 0);
    __syncthreads();
  }
#pragma unroll
  for (int mi = 0; mi < 4; ++mi)
#pragma unroll
    for (int ni = 0; ni < 4; ++ni) {
      int n = n0 + wc + ni * 16 + l16;
#pragma unroll
      for (int r = 0; r < 4; ++r) {
        int m = m0 + wr + mi * 16 + quad * 4 + r;
        float v = acc[mi][ni][r];
        v += resid[(size_t)m * N + n];
        C[(size_t)m * N + n] = v;
      }
    }
}

// ---------------------------------------------------------------------------
// Fused flash-style attention: scores + causal softmax + AV in one kernel.
// Q fragments hoisted into registers (loaded straight from global, invariant
// over all k-tiles) -> no Qs LDS; LDS = Ks+Vs+Ps = 53.2 KB -> 3 blocks/CU.
// ---------------------------------------------------------------------------
__global__ __launch_bounds__(256, 3) void attn_fused(
    const ushort* __restrict__ Qp, const ushort* __restrict__ Kp,
    const ushort* __restrict__ Vt, float* __restrict__ attn,
    ushort* __restrict__ Cc) {
  const int hb = blockIdx.x, qt = blockIdx.y;
  const int h = hb >> 2, b = hb & 3;
  const int q0 = qt * 64;
  const int nkt = (qt >> 1) + 1;   // 128-wide k-tiles covering k <= q0+63

  __shared__ ushort Ks[128 * 72];   // [k][c]
  __shared__ ushort Vs[64 * 136];   // [j][k] 128-wide k-tile, pad to 136
  __shared__ ushort Ps[64 * 136];   // [q][k] P tile bf16

  const int t = threadIdx.x;
  const int w = t >> 6, lane = t & 63;
  const int l16 = lane & 15, quad = lane >> 4;

  // ---- zero-fill strict-upper attn tiles for these 64 q-rows ----
  for (int ktz = nkt; ktz < 8; ++ktz) {
    const int k0 = ktz * 128;
#pragma unroll
    for (int i = 0; i < 4; ++i) {
      int cc = t + i * 256;
      int row = cc >> 4, cg = (cc & 15) * 8;
      float* dst = &attn[((size_t)hb * Sn + q0 + row) * Sn + k0 + cg];
      *(float4*)&dst[0] = make_float4(0.f, 0.f, 0.f, 0.f);
      *(float4*)&dst[4] = make_float4(0.f, 0.f, 0.f, 0.f);
    }
  }

  // ---- Q fragments straight to registers (wave-invariant across tiles) ----
  bf16x8 aq[2];
#pragma unroll
  for (int ks = 0; ks < 2; ++ks)
    aq[ks] = *(const bf16x8*)&Qp[((size_t)b * Sn + q0 + w * 16 + l16) * Dn +
                                 h * dHn + ks * 32 + quad * 8];

  float m_run[4], l_run[4];
#pragma unroll
  for (int r = 0; r < 4; ++r) { m_run[r] = -3e38f; l_run[r] = 0.f; }

  // ================= PASS 1: row max & sum =================
  for (int kt = 0; kt < nkt; ++kt) {
    const int k0 = kt * 128;
#pragma unroll
    for (int i = 0; i < 4; ++i) {
      int cc = t + i * 256;
      int row = cc >> 3, cg = (cc & 7) * 8;
      *(ulonglong2*)&Ks[row * 72 + cg] =
          *(const ulonglong2*)&Kp[((size_t)b * Sn + k0 + row) * Dn + h * dHn + cg];
    }
    __syncthreads();
    f32x4 s[8];
#pragma unroll
    for (int ni = 0; ni < 8; ++ni) {
      f32x4 a = {};
#pragma unroll
      for (int ks = 0; ks < 2; ++ks) {
        bf16x8 bk = *(const bf16x8*)&Ks[(ni * 16 + l16) * 72 + ks * 32 + quad * 8];
        a = __builtin_amdgcn_mfma_f32_16x16x32_bf16(aq[ks], bk, a, 0, 0, 0);
      }
      s[ni] = a;
    }
    float tmax[4] = {-3e38f, -3e38f, -3e38f, -3e38f};
#pragma unroll
    for (int ni = 0; ni < 8; ++ni)
#pragma unroll
      for (int r = 0; r < 4; ++r) {
        int kg = k0 + ni * 16 + l16;
        int qg = q0 + w * 16 + quad * 4 + r;
        float v = (kg <= qg) ? s[ni][r] * 0.125f : -3e38f;
        s[ni][r] = v;
        tmax[r] = fmaxf(tmax[r], v);
      }
#pragma unroll
    for (int d = 1; d < 16; d <<= 1)
#pragma unroll
      for (int r = 0; r < 4; ++r)
        tmax[r] = fmaxf(tmax[r], __shfl_xor(tmax[r], d));
    float mnew[4], tsum[4] = {0.f, 0.f, 0.f, 0.f};
#pragma unroll
    for (int r = 0; r < 4; ++r) mnew[r] = fmaxf(m_run[r], tmax[r]);
#pragma unroll
    for (int ni = 0; ni < 8; ++ni)
#pragma unroll
      for (int r = 0; r < 4; ++r) tsum[r] += __expf(s[ni][r] - mnew[r]);
#pragma unroll
    for (int d = 1; d < 16; d <<= 1)
#pragma unroll
      for (int r = 0; r < 4; ++r) tsum[r] += __shfl_xor(tsum[r], d);
#pragma unroll
    for (int r = 0; r < 4; ++r) {
      l_run[r] = l_run[r] * __expf(m_run[r] - mnew[r]) + tsum[r];
      m_run[r] = mnew[r];
    }
    __syncthreads();
  }
  float inv_l[4];
#pragma unroll
  for (int r = 0; r < 4; ++r) inv_l[r] = 1.0f / l_run[r];

  // ================= PASS 2: P writes + O accumulate =================
  f32x4 acc_o[4] = {};
  for (int kt = 0; kt < nkt; ++kt) {
    const int k0 = kt * 128;
#pragma unroll
    for (int i = 0; i < 4; ++i) {
      int cc = t + i * 256;
      int row = cc >> 3, cg = (cc & 7) * 8;
      *(ulonglong2*)&Ks[row * 72 + cg] =
          *(const ulonglong2*)&Kp[((size_t)b * Sn + k0 + row) * Dn + h * dHn + cg];
    }
#pragma unroll
    for (int i = 0; i < 4; ++i) {
      int cc = t + i * 256;
      int row = cc >> 4, cg = (cc & 15) * 8;
      *(ulonglong2*)&Vs[row * 136 + cg] =
          *(const ulonglong2*)&Vt[((size_t)b * Dn + h * dHn + row) * Sn + k0 + cg];
    }
    __syncthreads();
    f32x4 s[8];
#pragma unroll
    for (int ni = 0; ni < 8; ++ni) {
      f32x4 a = {};
#pragma unroll
      for (int ks = 0; ks < 2; ++ks) {
        bf16x8 bk = *(const bf16x8*)&Ks[(ni * 16 + l16) * 72 + ks * 32 + quad * 8];
        a = __builtin_amdgcn_mfma_f32_16x16x32_bf16(aq[ks], bk, a, 0, 0, 0);
      }
      s[ni] = a;
    }
    // P = exp(s - m) / l ; masked entries give exp(-huge) == 0
#pragma unroll
    for (int ni = 0; ni < 8; ++ni)
#pragma unroll
      for (int r = 0; r < 4; ++r) {
        int kg = k0 + ni * 16 + l16;
        int qg = q0 + w * 16 + quad * 4 + r;
        float v = (kg <= qg) ? s[ni][r] * 0.125f : -3e38f;
        float p = __expf(v - m_run[r]) * inv_l[r];
        Ps[(w * 16 + quad * 4 + r) * 136 + ni * 16 + l16] = f2bf(p);
      }
    // O += P @ V^T-form (A = own wave's 16 P rows; B = Vs rows j, k-contig)
#pragma unroll
    for (int ks = 0; ks < 4; ++ks) {
      bf16x8 ap = *(const bf16x8*)&Ps[(w * 16 + l16) * 136 + ks * 32 + quad * 8];
#pragma unroll
      for (int ni = 0; ni < 4; ++ni) {
        bf16x8 bv = *(const bf16x8*)&Vs[(ni * 16 + l16) * 136 + ks * 32 + quad * 8];
        acc_o[ni] = __builtin_amdgcn_mfma_f32_16x16x32_bf16(ap, bv, acc_o[ni], 0, 0, 0);
      }
    }
    __syncthreads();   // all waves' Ps written before cross-wave attn store
    // coalesced fp32 attn store from Ps
#pragma unroll
    for (int i = 0; i < 4; ++i) {
      int cc = t + i * 256;
      int row = cc >> 4, cg = (cc & 15) * 8;
      bf16x8 pv = *(const bf16x8*)&Ps[row * 136 + cg];
      float* dst = &attn[((size_t)hb * Sn + q0 + row) * Sn + k0 + cg];
      *(float4*)&dst[0] = make_float4(bf2f((ushort)pv[0]), bf2f((ushort)pv[1]),
                                      bf2f((ushort)pv[2]), bf2f((ushort)pv[3]));
      *(float4*)&dst[4] = make_float4(bf2f((ushort)pv[4]), bf2f((ushort)pv[5]),
                                      bf2f((ushort)pv[6]), bf2f((ushort)pv[7]));
    }
  }
  // ---- O epilogue -> concat bf16 [B*S, D] ----
#pragma unroll
  for (int ni = 0; ni < 4; ++ni)
#pragma unroll
    for (int r = 0; r < 4; ++r) {
      int q = q0 + w * 16 + quad * 4 + r;
      int j = ni * 16 + l16;
      Cc[((size_t)b * Sn + q) * Dn + h * dHn + j] = f2bf(acc_o[ni][r]);
    }
}

// ---------------------------------------------------------------------------
// In-place row LayerNorm on out[B*S, D].  grid (B*S), 256 threads.
// ---------------------------------------------------------------------------
__global__ __launch_bounds__(256) void ln_kernel(
    float* __restrict__ out, const float* __restrict__ gamma,
    const float* __restrict__ beta) {
  const int row = blockIdx.x;
  float* p = out + (size_t)row * Dn;
  const int t = threadIdx.x;
  float v[4];
  float s = 0.f, s2 = 0.f;
#pragma unroll
  for (int i = 0; i < 4; ++i) {
    v[i] = p[t + i * 256];
    s += v[i];
    s2 += v[i] * v[i];
  }
  __shared__ float r1[256], r2[256];
  r1[t] = s; r2[t] = s2;
  __syncthreads();
  for (int st = 128; st > 0; st >>= 1) {
    if (t < st) { r1[t] += r1[t + st]; r2[t] += r2[t + st]; }
    __syncthreads();
  }
  const float mu  = r1[0] * (1.0f / Dn);
  const float var = r2[0] * (1.0f / Dn) - mu * mu;
  const float rstd = rsqrtf(var + 1e-5f);
#pragma unroll
  for (int i = 0; i < 4; ++i) {
    int c = t + i * 256;
    p[c] = (v[i] - mu) * rstd * gamma[c] + beta[c];
  }
}

// ---------------------------------------------------------------------------
extern "C" void kernel_launch(void* const* d_in, const int* in_sizes, int n_in,
                              void* d_out, int out_size, void* d_ws, size_t ws_size,
                              hipStream_t stream) {
  const float* q_in  = (const float*)d_in[0];
  const float* k_in  = (const float*)d_in[1];
  const float* v_in  = (const float*)d_in[2];
  const float* Wq    = (const float*)d_in[3];
  const float* Wk    = (const float*)d_in[4];
  const float* Wv    = (const float*)d_in[5];
  const float* Wo    = (const float*)d_in[6];
  const float* gamma = (const float*)d_in[7];
  const float* beta  = (const float*)d_in[8];

  float* out  = (float*)d_out;                // [B,S,D]
  float* attn = out + (size_t)Bn * Sn * Dn;   // [H,B,S,S]

  ushort* ws  = (ushort*)d_ws;
  ushort* qbf = ws;                           // [B*S, D] bf16  (q|k|v contiguous)
  ushort* kbf = qbf + QNE;
  ushort* vbf = kbf + QNE;
  ushort* WqT = vbf + QNE;                    // [N,K] bf16, contiguous x4
  ushort* WkT = WqT + (size_t)Dn * Dn;
  ushort* WvT = WkT + (size_t)Dn * Dn;
  ushort* WoT = WvT + (size_t)Dn * Dn;
  ushort* Qp  = WoT + (size_t)Dn * Dn;        // [B*S, D] bf16  (Qp|Kp|Vt contiguous)
  ushort* Kp  = Qp + QNE;
  ushort* Vt  = Kp + QNE;                     // [B][D][S] bf16
  ushort* Cc  = Vt + QNE;                     // [B*S, D] bf16

  (void)kbf; (void)vbf; (void)WkT; (void)WvT; (void)Kp;

  cast3_kernel<<<dim3(QNE / 1024, 3), 256, 0, stream>>>(q_in, k_in, v_in, qbf);
  transpose4_kernel<<<dim3(Dn / 64, Dn / 64, 4), 256, 0, stream>>>(Wq, Wk, Wv, Wo, WqT);

  // batched QKV projections: 768 blocks -> ~3 blocks/CU
  qkv_gemm<<<dim3(Dn / 128, MROWS / 128, 3), 256, 0, stream>>>(qbf, WqT, Qp);

  attn_fused<<<dim3(HB, Sn / 64), 256, 0, stream>>>(Qp, Kp, Vt, attn, Cc);

  gemm_out<<<dim3(Dn / 128, MROWS / 128), 256, 0, stream>>>(Cc, WoT, q_in, out, MROWS, Dn, Dn);
  ln_kernel<<<MROWS, 256, 0, stream>>>(out, gamma, beta);
}

// Round 2
// 462.326 us; speedup vs baseline: 1.1638x; 1.0045x over previous
//
#include <hip/hip_runtime.h>
#include <hip/hip_bf16.h>

// Problem constants (fixed by the reference)
#define Bn   4
#define Sn   1024
#define Dn   1024
#define Hn   16
#define dHn  64
#define HB   (Hn * Bn)     // 64
#define MROWS (Bn * Sn)    // 4096
#define QNE  ((size_t)Bn * Sn * Dn)   // 4M elements per activation tensor

typedef __attribute__((ext_vector_type(8))) short bf16x8;
typedef __attribute__((ext_vector_type(4))) float f32x4;

__device__ __forceinline__ ushort f2bf(float x) {
  union { float f; unsigned u; } v; v.f = x;
  unsigned r = v.u + 0x7FFF + ((v.u >> 16) & 1);   // round-to-nearest-even
  return (ushort)(r >> 16);
}
__device__ __forceinline__ float bf2f(ushort u) {
  union { unsigned u; float f; } v; v.u = ((unsigned)u) << 16; return v.f;
}

// async global->LDS, 16B per lane; lds dest = wave-uniform base + lane*16
__device__ __forceinline__ void load_lds16(const void* g, void* l) {
  __builtin_amdgcn_global_load_lds(
      (const __attribute__((address_space(1))) unsigned int*)g,
      (__attribute__((address_space(3))) unsigned int*)l, 16, 0, 0);
}

// ---------------------------------------------------------------------------
// fp32 -> bf16 flat cast for q,k,v in ONE launch.  grid (QNE/1024, 3).
// ---------------------------------------------------------------------------
__global__ __launch_bounds__(256) void cast3_kernel(
    const float* __restrict__ q, const float* __restrict__ k,
    const float* __restrict__ v, ushort* __restrict__ outb) {
  const float* in = blockIdx.y == 0 ? q : (blockIdx.y == 1 ? k : v);
  ushort* out = outb + (size_t)blockIdx.y * QNE;
  int idx = blockIdx.x * 256 + threadIdx.x;   // float4 index
  float4 x = *(const float4*)&in[(size_t)idx * 4];
  ushort4 o;
  o.x = f2bf(x.x); o.y = f2bf(x.y); o.z = f2bf(x.z); o.w = f2bf(x.w);
  *(ushort4*)&out[(size_t)idx * 4] = o;
}

// ---------------------------------------------------------------------------
// W [K,N] fp32 -> WT [N,K] bf16 for all 4 weights in ONE launch.
// Tile 64x64.  grid (Dn/64, Dn/64, 4).
// ---------------------------------------------------------------------------
__global__ __launch_bounds__(256) void transpose4_kernel(
    const float* __restrict__ Wq, const float* __restrict__ Wk,
    const float* __restrict__ Wv, const float* __restrict__ Wo,
    ushort* __restrict__ WTb) {
  const int z = blockIdx.z;
  const float* W = z == 0 ? Wq : (z == 1 ? Wk : (z == 2 ? Wv : Wo));
  ushort* WT = WTb + (size_t)z * Dn * Dn;
  __shared__ ushort T[64 * 72];   // [n][k], stride 72
  const int k0 = blockIdx.y * 64, n0 = blockIdx.x * 64;
  const int t = threadIdx.x;
  const int r = t >> 4, c4 = (t & 15) * 4;
#pragma unroll
  for (int i = 0; i < 4; ++i) {
    int row = r + i * 16;   // k within tile
    float4 v = *(const float4*)&W[(size_t)(k0 + row) * Dn + n0 + c4];
    T[(c4 + 0) * 72 + row] = f2bf(v.x);
    T[(c4 + 1) * 72 + row] = f2bf(v.y);
    T[(c4 + 2) * 72 + row] = f2bf(v.z);
    T[(c4 + 3) * 72 + row] = f2bf(v.w);
  }
  __syncthreads();
#pragma unroll
  for (int i = 0; i < 2; ++i) {
    int c = t + i * 256;
    int n = c >> 3, kg = (c & 7) * 8;
    *(ulonglong2*)&WT[(size_t)(n0 + n) * Dn + k0 + kg] =
        *(const ulonglong2*)&T[n * 72 + kg];
  }
}

// ---------------------------------------------------------------------------
// Batched QKV projection GEMM: grid (Dn/128, MROWS/128, 3) = 768 blocks.
// XCD-aware tile remap: the 8 blocks sharing an A-panel all get the same
// hardware x -> same XCD; each XCD's L2 holds 4 A-panels + all B = 3 MB.
// z=0: Qp (bf16 row-major), z=1: Kp, z=2: Vt (batch-transposed, via LDS
// transpose so stores are 256B-contiguous along s instead of 8B scatter).
// ---------------------------------------------------------------------------
__global__ __launch_bounds__(256, 3) void qkv_gemm(
    const ushort* __restrict__ Ab, const ushort* __restrict__ Bb,
    ushort* __restrict__ Cb) {
  const int z = blockIdx.z;
  const ushort* A  = Ab + (size_t)z * QNE;
  const ushort* Bt = Bb + (size_t)z * Dn * Dn;
  ushort* C        = Cb + (size_t)z * QNE;
  const int N = Dn, K = Dn;

  __shared__ ushort lds[17408];   // staging 16KB; epilogue Cs 34KB (reused)
  ushort* As = lds;          // 128 x 32 (unpadded, k-contig)
  ushort* Bs = lds + 4096;   // 128 x 32
  const int t = threadIdx.x;
  const int w = t >> 6, lane = t & 63;
  const int wr = (w >> 1) * 64, wc = (w & 1) * 64;
  const int l16 = lane & 15, quad = lane >> 4;
  // XCD swizzle: hw (x,y) -> tile (nf&7, nf>>3), nf = x*32 + y.
  const int flat = blockIdx.y * 8 + blockIdx.x;
  const int nf = (flat & 7) * 32 + (flat >> 3);
  const int m0 = (nf >> 3) * 128, n0 = (nf & 7) * 128;
  const int srow = (lane >> 2);
  const int scol = (lane & 3) * 8;
  f32x4 acc[4][4] = {};
  for (int k0 = 0; k0 < K; k0 += 32) {
#pragma unroll
    for (int c = 0; c < 2; ++c) {
      int row = w * 32 + c * 16 + srow;
      load_lds16(&A[(size_t)(m0 + row) * K + k0 + scol],
                 &As[(size_t)w * 1024 + c * 512]);
      load_lds16(&Bt[(size_t)(n0 + row) * K + k0 + scol],
                 &Bs[(size_t)w * 1024 + c * 512]);
    }
    __syncthreads();
    bf16x8 af[4], bfr[4];
#pragma unroll
    for (int mi = 0; mi < 4; ++mi)
      af[mi] = *(const bf16x8*)&As[(wr + mi * 16 + l16) * 32 + quad * 8];
#pragma unroll
    for (int ni = 0; ni < 4; ++ni)
      bfr[ni] = *(const bf16x8*)&Bs[(wc + ni * 16 + l16) * 32 + quad * 8];
#pragma unroll
    for (int mi = 0; mi < 4; ++mi)
#pragma unroll
      for (int ni = 0; ni < 4; ++ni)
        acc[mi][ni] = __builtin_amdgcn_mfma_f32_16x16x32_bf16(
            af[mi], bfr[ni], acc[mi][ni], 0, 0, 0);
    __syncthreads();
  }
  if (z == 2) {   // Vt: C[(b*Dn + n)*Sn + s]; transpose in LDS, store along s
    ushort* Cs = lds;   // [n 0..127][m 0..127], stride 136 (= 17408 ushorts)
#pragma unroll
    for (int mi = 0; mi < 4; ++mi)
#pragma unroll
      for (int ni = 0; ni < 4; ++ni) {
        int col = wc + ni * 16 + l16;
#pragma unroll
        for (int r = 0; r < 4; ++r)
          Cs[col * 136 + wr + mi * 16 + quad * 4 + r] = f2bf(acc[mi][ni][r]);
      }
    __syncthreads();
    const int b = m0 >> 10, s0 = m0 & 1023;   // 128-row tile within one batch
#pragma unroll
    for (int i = 0; i < 8; ++i) {
      int c = t + i * 256;
      int nl = c >> 4, mg = (c & 15) * 8;
      *(ulonglong2*)&C[((size_t)b * Dn + n0 + nl) * Sn + s0 + mg] =
          *(const ulonglong2*)&Cs[nl * 136 + mg];
    }
  } else {        // Qp/Kp: bf16 row-major via LDS for coalesced stores
    ushort* Cs = lds;   // 128 x 136
#pragma unroll
    for (int mi = 0; mi < 4; ++mi)
#pragma unroll
      for (int ni = 0; ni < 4; ++ni) {
        int col = wc + ni * 16 + l16;
#pragma unroll
        for (int r = 0; r < 4; ++r)
          Cs[(wr + mi * 16 + quad * 4 + r) * 136 + col] = f2bf(acc[mi][ni][r]);
      }
    __syncthreads();
#pragma unroll
    for (int i = 0; i < 8; ++i) {
      int c = t + i * 256;
      int row = c >> 4, cg = (c & 15) * 8;
      *(ulonglong2*)&C[(size_t)(m0 + row) * N + n0 + cg] =
          *(const ulonglong2*)&Cs[row * 136 + cg];
    }
  }
}

// ---------------------------------------------------------------------------
// Output projection GEMM (BT form): C[M,N] = A[M,K] @ Bt[N,K]^T + resid,
// fp32 out.  Tile 128x128, BK=32, 4 waves.  Same XCD swizzle as qkv_gemm.
// ---------------------------------------------------------------------------
__global__ __launch_bounds__(256) void gemm_out(
    const ushort* __restrict__ A, const ushort* __restrict__ Bt,
    const float* __restrict__ resid, float* __restrict__ C,
    int M, int N, int K) {
  __shared__ ushort lds[8192];
  ushort* As = lds;
  ushort* Bs = lds + 4096;
  const int t = threadIdx.x;
  const int w = t >> 6, lane = t & 63;
  const int wr = (w >> 1) * 64, wc = (w & 1) * 64;
  const int l16 = lane & 15, quad = lane >> 4;
  const int flat = blockIdx.y * 8 + blockIdx.x;
  const int nf = (flat & 7) * 32 + (flat >> 3);
  const int m0 = (nf >> 3) * 128, n0 = (nf & 7) * 128;
  const int srow = (lane >> 2);
  const int scol = (lane & 3) * 8;
  f32x4 acc[4][4] = {};
  for (int k0 = 0; k0 < K; k0 += 32) {
#pragma unroll
    for (int c = 0; c < 2; ++c) {
      int row = w * 32 + c * 16 + srow;
      load_lds16(&A[(size_t)(m0 + row) * K + k0 + scol],
                 &As[(size_t)w * 1024 + c * 512]);
      load_lds16(&Bt[(size_t)(n0 + row) * K + k0 + scol],
                 &Bs[(size_t)w * 1024 + c * 512]);
    }
    __syncthreads();
    bf16x8 af[4], bfr[4];
#pragma unroll
    for (int mi = 0; mi < 4; ++mi)
      af[mi] = *(const bf16x8*)&As[(wr + mi * 16 + l16) * 32 + quad * 8];
#pragma unroll
    for (int ni = 0; ni < 4; ++ni)
      bfr[ni] = *(const bf16x8*)&Bs[(wc + ni * 16 + l16) * 32 + quad * 8];
#pragma unroll
    for (int mi = 0; mi < 4; ++mi)
#pragma unroll
      for (int ni = 0; ni < 4; ++ni)
        acc[mi][ni] = __builtin_amdgcn_mfma_f32_16x16x32_bf16(
            af[mi], bfr[ni], acc[mi][ni], 0, 0, 0);
    __syncthreads();
  }
#pragma unroll
  for (int mi = 0; mi < 4; ++mi)
#pragma unroll
    for (int ni = 0; ni < 4; ++ni) {
      int n = n0 + wc + ni * 16 + l16;
#pragma unroll
      for (int r = 0; r < 4; ++r) {
        int m = m0 + wr + mi * 16 + quad * 4 + r;
        float v = acc[mi][ni][r];
        v += resid[(size_t)m * N + n];
        C[(size_t)m * N + n] = v;
      }
    }
}

// ---------------------------------------------------------------------------
// Fused flash-style attention.  Q in registers; LDS = Ks+Vs+Ps -> 3 blocks/CU.
// Even q-tiles: the diagonal k-tile's upper 64 columns are 100% masked ->
// skip their K/V loads, QK & PV MFMAs, and exps (wave-uniform guards inside
// fully-unrolled loops so s[]/acc stay in registers).
// ---------------------------------------------------------------------------
__global__ __launch_bounds__(256, 3) void attn_fused(
    const ushort* __restrict__ Qp, const ushort* __restrict__ Kp,
    const ushort* __restrict__ Vt, float* __restrict__ attn,
    ushort* __restrict__ Cc) {
  const int hb = blockIdx.x, qt = blockIdx.y;
  const int h = hb >> 2, b = hb & 3;
  const int q0 = qt * 64;
  const int nkt = (qt >> 1) + 1;   // 128-wide k-tiles covering k <= q0+63

  __shared__ ushort Ks[128 * 72];   // [k][c]
  __shared__ ushort Vs[64 * 136];   // [j][k] 128-wide k-tile, pad to 136
  __shared__ ushort Ps[64 * 136];   // [q][k] P tile bf16

  const int t = threadIdx.x;
  const int w = t >> 6, lane = t & 63;
  const int l16 = lane & 15, quad = lane >> 4;

  // ---- zero-fill strict-upper attn tiles for these 64 q-rows ----
  for (int ktz = nkt; ktz < 8; ++ktz) {
    const int k0 = ktz * 128;
#pragma unroll
    for (int i = 0; i < 4; ++i) {
      int cc = t + i * 256;
      int row = cc >> 4, cg = (cc & 15) * 8;
      float* dst = &attn[((size_t)hb * Sn + q0 + row) * Sn + k0 + cg];
      *(float4*)&dst[0] = make_float4(0.f, 0.f, 0.f, 0.f);
      *(float4*)&dst[4] = make_float4(0.f, 0.f, 0.f, 0.f);
    }
  }

  // ---- Q fragments straight to registers (wave-invariant across tiles) ----
  bf16x8 aq[2];
#pragma unroll
  for (int ks = 0; ks < 2; ++ks)
    aq[ks] = *(const bf16x8*)&Qp[((size_t)b * Sn + q0 + w * 16 + l16) * Dn +
                                 h * dHn + ks * 32 + quad * 8];

  float m_run[4], l_run[4];
#pragma unroll
  for (int r = 0; r < 4; ++r) { m_run[r] = -3e38f; l_run[r] = 0.f; }

  // ================= PASS 1: row max & sum =================
  for (int kt = 0; kt < nkt; ++kt) {
    const int k0 = kt * 128;
    const bool halfT = (kt == nkt - 1) && ((qt & 1) == 0);
    const int nni = halfT ? 4 : 8;
    const int kiters = halfT ? 2 : 4;
#pragma unroll
    for (int i = 0; i < 4; ++i) {
      if (i < kiters) {
        int cc = t + i * 256;
        int row = cc >> 3, cg = (cc & 7) * 8;
        *(ulonglong2*)&Ks[row * 72 + cg] =
            *(const ulonglong2*)&Kp[((size_t)b * Sn + k0 + row) * Dn + h * dHn + cg];
      }
    }
    __syncthreads();
    f32x4 s[8];
#pragma unroll
    for (int ni = 0; ni < 8; ++ni) {
      if (ni < nni) {
        f32x4 a = {};
#pragma unroll
        for (int ks = 0; ks < 2; ++ks) {
          bf16x8 bk = *(const bf16x8*)&Ks[(ni * 16 + l16) * 72 + ks * 32 + quad * 8];
          a = __builtin_amdgcn_mfma_f32_16x16x32_bf16(aq[ks], bk, a, 0, 0, 0);
        }
        s[ni] = a;
      }
    }
    float tmax[4] = {-3e38f, -3e38f, -3e38f, -3e38f};
#pragma unroll
    for (int ni = 0; ni < 8; ++ni) {
      if (ni < nni)
#pragma unroll
        for (int r = 0; r < 4; ++r) {
          int kg = k0 + ni * 16 + l16;
          int qg = q0 + w * 16 + quad * 4 + r;
          float v = (kg <= qg) ? s[ni][r] * 0.125f : -3e38f;
          s[ni][r] = v;
          tmax[r] = fmaxf(tmax[r], v);
        }
    }
#pragma unroll
    for (int d = 1; d < 16; d <<= 1)
#pragma unroll
      for (int r = 0; r < 4; ++r)
        tmax[r] = fmaxf(tmax[r], __shfl_xor(tmax[r], d));
    float mnew[4], tsum[4] = {0.f, 0.f, 0.f, 0.f};
#pragma unroll
    for (int r = 0; r < 4; ++r) mnew[r] = fmaxf(m_run[r], tmax[r]);
#pragma unroll
    for (int ni = 0; ni < 8; ++ni) {
      if (ni < nni)
#pragma unroll
        for (int r = 0; r < 4; ++r) tsum[r] += __expf(s[ni][r] - mnew[r]);
    }
#pragma unroll
    for (int d = 1; d < 16; d <<= 1)
#pragma unroll
      for (int r = 0; r < 4; ++r) tsum[r] += __shfl_xor(tsum[r], d);
#pragma unroll
    for (int r = 0; r < 4; ++r) {
      l_run[r] = l_run[r] * __expf(m_run[r] - mnew[r]) + tsum[r];
      m_run[r] = mnew[r];
    }
    __syncthreads();
  }
  float inv_l[4];
#pragma unroll
  for (int r = 0; r < 4; ++r) inv_l[r] = 1.0f / l_run[r];

  // ================= PASS 2: P writes + O accumulate =================
  f32x4 acc_o[4] = {};
  for (int kt = 0; kt < nkt; ++kt) {
    const int k0 = kt * 128;
    const bool halfT = (kt == nkt - 1) && ((qt & 1) == 0);
    const int nni = halfT ? 4 : 8;
    const int kiters = halfT ? 2 : 4;
    const int nks = halfT ? 2 : 4;
#pragma unroll
    for (int i = 0; i < 4; ++i) {
      if (i < kiters) {
        int cc = t + i * 256;
        int row = cc >> 3, cg = (cc & 7) * 8;
        *(ulonglong2*)&Ks[row * 72 + cg] =
            *(const ulonglong2*)&Kp[((size_t)b * Sn + k0 + row) * Dn + h * dHn + cg];
      }
    }
#pragma unroll
    for (int i = 0; i < 4; ++i) {
      if (i < 2 * kiters) {   // V: 64 rows x (kiters*32) k-cols
        int cc = t + i * 256;
        int row, cg;
        if (halfT) { row = cc >> 3; cg = (cc & 7) * 8; }
        else       { row = cc >> 4; cg = (cc & 15) * 8; }
        *(ulonglong2*)&Vs[row * 136 + cg] =
            *(const ulonglong2*)&Vt[((size_t)b * Dn + h * dHn + row) * Sn + k0 + cg];
      }
    }
    __syncthreads();
    f32x4 s[8];
#pragma unroll
    for (int ni = 0; ni < 8; ++ni) {
      if (ni < nni) {
        f32x4 a = {};
#pragma unroll
        for (int ks = 0; ks < 2; ++ks) {
          bf16x8 bk = *(const bf16x8*)&Ks[(ni * 16 + l16) * 72 + ks * 32 + quad * 8];
          a = __builtin_amdgcn_mfma_f32_16x16x32_bf16(aq[ks], bk, a, 0, 0, 0);
        }
        s[ni] = a;
      }
    }
    // P = exp(s - m) / l ; masked entries give exp(-huge) == 0
#pragma unroll
    for (int ni = 0; ni < 8; ++ni)
#pragma unroll
      for (int r = 0; r < 4; ++r) {
        float p;
        if (ni < nni) {
          int kg = k0 + ni * 16 + l16;
          int qg = q0 + w * 16 + quad * 4 + r;
          float v = (kg <= qg) ? s[ni][r] * 0.125f : -3e38f;
          p = __expf(v - m_run[r]) * inv_l[r];
        } else {
          p = 0.f;
        }
        Ps[(w * 16 + quad * 4 + r) * 136 + ni * 16 + l16] = f2bf(p);
      }
    // O += P @ V  (skip k-slots that are all-zero on half tiles)
#pragma unroll
    for (int ks = 0; ks < 4; ++ks) {
      if (ks < nks) {
        bf16x8 ap = *(const bf16x8*)&Ps[(w * 16 + l16) * 136 + ks * 32 + quad * 8];
#pragma unroll
        for (int ni = 0; ni < 4; ++ni) {
          bf16x8 bv = *(const bf16x8*)&Vs[(ni * 16 + l16) * 136 + ks * 32 + quad * 8];
          acc_o[ni] = __builtin_amdgcn_mfma_f32_16x16x32_bf16(ap, bv, acc_o[ni], 0, 0, 0);
        }
      }
    }
    __syncthreads();   // all waves' Ps written before cross-wave attn store
    // coalesced fp32 attn store from Ps
#pragma unroll
    for (int i = 0; i < 4; ++i) {
      int cc = t + i * 256;
      int row = cc >> 4, cg = (cc & 15) * 8;
      bf16x8 pv = *(const bf16x8*)&Ps[row * 136 + cg];
      float* dst = &attn[((size_t)hb * Sn + q0 + row) * Sn + k0 + cg];
      *(float4*)&dst[0] = make_float4(bf2f((ushort)pv[0]), bf2f((ushort)pv[1]),
                                      bf2f((ushort)pv[2]), bf2f((ushort)pv[3]));
      *(float4*)&dst[4] = make_float4(bf2f((ushort)pv[4]), bf2f((ushort)pv[5]),
                                      bf2f((ushort)pv[6]), bf2f((ushort)pv[7]));
    }
  }
  // ---- O epilogue -> concat bf16 [B*S, D] ----
#pragma unroll
  for (int ni = 0; ni < 4; ++ni)
#pragma unroll
    for (int r = 0; r < 4; ++r) {
      int q = q0 + w * 16 + quad * 4 + r;
      int j = ni * 16 + l16;
      Cc[((size_t)b * Sn + q) * Dn + h * dHn + j] = f2bf(acc_o[ni][r]);
    }
}

// ---------------------------------------------------------------------------
// In-place row LayerNorm on out[B*S, D].  grid (B*S), 256 threads.
// float4 loads + wave shfl reduce (one __syncthreads total).
// ---------------------------------------------------------------------------
__global__ __launch_bounds__(256) void ln_kernel(
    float* __restrict__ out, const float* __restrict__ gamma,
    const float* __restrict__ beta) {
  const int row = blockIdx.x;
  float* p = out + (size_t)row * Dn;
  const int t = threadIdx.x;
  float4 x = *(const float4*)&p[t * 4];
  float s  = x.x + x.y + x.z + x.w;
  float s2 = x.x * x.x + x.y * x.y + x.z * x.z + x.w * x.w;
#pragma unroll
  for (int d = 1; d < 64; d <<= 1) {
    s  += __shfl_xor(s, d);
    s2 += __shfl_xor(s2, d);
  }
  __shared__ float a1[4], a2[4];
  const int w = t >> 6, lane = t & 63;
  if (lane == 0) { a1[w] = s; a2[w] = s2; }
  __syncthreads();
  s  = a1[0] + a1[1] + a1[2] + a1[3];
  s2 = a2[0] + a2[1] + a2[2] + a2[3];
  const float mu  = s * (1.0f / Dn);
  const float var = s2 * (1.0f / Dn) - mu * mu;
  const float rstd = rsqrtf(var + 1e-5f);
  float4 g  = *(const float4*)&gamma[t * 4];
  float4 be = *(const float4*)&beta[t * 4];
  float4 o;
  o.x = (x.x - mu) * rstd * g.x + be.x;
  o.y = (x.y - mu) * rstd * g.y + be.y;
  o.z = (x.z - mu) * rstd * g.z + be.z;
  o.w = (x.w - mu) * rstd * g.w + be.w;
  *(float4*)&p[t * 4] = o;
}

// ---------------------------------------------------------------------------
extern "C" void kernel_launch(void* const* d_in, const int* in_sizes, int n_in,
                              void* d_out, int out_size, void* d_ws, size_t ws_size,
                              hipStream_t stream) {
  const float* q_in  = (const float*)d_in[0];
  const float* k_in  = (const float*)d_in[1];
  const float* v_in  = (const float*)d_in[2];
  const float* Wq    = (const float*)d_in[3];
  const float* Wk    = (const float*)d_in[4];
  const float* Wv    = (const float*)d_in[5];
  const float* Wo    = (const float*)d_in[6];
  const float* gamma = (const float*)d_in[7];
  const float* beta  = (const float*)d_in[8];

  float* out  = (float*)d_out;                // [B,S,D]
  float* attn = out + (size_t)Bn * Sn * Dn;   // [H,B,S,S]

  ushort* ws  = (ushort*)d_ws;
  ushort* qbf = ws;                           // [B*S, D] bf16  (q|k|v contiguous)
  ushort* kbf = qbf + QNE;
  ushort* vbf = kbf + QNE;
  ushort* WqT = vbf + QNE;                    // [N,K] bf16, contiguous x4
  ushort* WkT = WqT + (size_t)Dn * Dn;
  ushort* WvT = WkT + (size_t)Dn * Dn;
  ushort* WoT = WvT + (size_t)Dn * Dn;
  ushort* Qp  = WoT + (size_t)Dn * Dn;        // [B*S, D] bf16  (Qp|Kp|Vt contiguous)
  ushort* Kp  = Qp + QNE;
  ushort* Vt  = Kp + QNE;                     // [B][D][S] bf16
  ushort* Cc  = Vt + QNE;                     // [B*S, D] bf16

  (void)kbf; (void)vbf; (void)WkT; (void)WvT; (void)Kp;

  cast3_kernel<<<dim3(QNE / 1024, 3), 256, 0, stream>>>(q_in, k_in, v_in, qbf);
  transpose4_kernel<<<dim3(Dn / 64, Dn / 64, 4), 256, 0, stream>>>(Wq, Wk, Wv, Wo, WqT);

  // batched QKV projections: 768 blocks -> ~3 blocks/CU, XCD-swizzled
  qkv_gemm<<<dim3(Dn / 128, MROWS / 128, 3), 256, 0, stream>>>(qbf, WqT, Qp);

  attn_fused<<<dim3(HB, Sn / 64), 256, 0, stream>>>(Qp, Kp, Vt, attn, Cc);

  gemm_out<<<dim3(Dn / 128, MROWS / 128), 256, 0, stream>>>(Cc, WoT, q_in, out, MROWS, Dn, Dn);
  ln_kernel<<<MROWS, 256, 0, stream>>>(out, gamma, beta);
}